// Round 1
// baseline (3686.692 us; speedup 1.0000x reference)
//
#include <hip/hip_runtime.h>
#include <math.h>

// Problem constants (from reference)
#define N0_C 3072000
#define N1_C 204800
#define N2_C 20480
#define N3_C 4096
#define E0_C 3072000
#define E1_C 204800
#define E2_C 20480
#define DIN_C 100
#define DH_C 256
#define DOUT_C 47

// ---------------------------------------------------------------------------
// Edge scatter: one wave per edge. Gathers x[src] row, atomically adds into
// agg[dst] row, lane 0 bumps cnt[dst].
// ---------------------------------------------------------------------------
template <int D>
__global__ __launch_bounds__(256) void scatter_mean_accum(
    const float* __restrict__ x, const int* __restrict__ src,
    const int* __restrict__ dst, float* __restrict__ agg,
    float* __restrict__ cnt, int E) {
  int wave = (blockIdx.x * blockDim.x + threadIdx.x) >> 6;
  int lane = threadIdx.x & 63;
  if (wave >= E) return;
  int s = src[wave];
  int d = dst[wave];
  const float* xr = x + (long long)s * D;
  float* ar = agg + (long long)d * D;
#pragma unroll
  for (int f = lane; f < D; f += 64) {
    atomicAdd(&ar[f], xr[f]);
  }
  if (lane == 0) atomicAdd(&cnt[d], 1.0f);
}

// ---------------------------------------------------------------------------
// Row transform: out[row] = relu( (agg[row]/max(cnt,1)) @ Wl + bl + xt[row] @ Wr )
// 256 threads = 256 output dims; TILE=8 rows per block.
// Row values are wave-uniform loads (scalar pipe); weight loads are coalesced
// and L2-hot. Scale by 1/cnt is folded to the epilogue (linearity).
// ---------------------------------------------------------------------------
template <int DIN_T>
__global__ __launch_bounds__(256) void transform_relu(
    const float* __restrict__ agg, const float* __restrict__ cnt,
    const float* __restrict__ xt, const float* __restrict__ Wl,
    const float* __restrict__ Wr, const float* __restrict__ bl,
    float* __restrict__ out) {
  constexpr int TILE = 8;
  const int row0 = blockIdx.x * TILE;
  const int j = threadIdx.x;  // output dim 0..255

  float accL[TILE];
  float accR[TILE];
#pragma unroll
  for (int r = 0; r < TILE; ++r) { accL[r] = 0.f; accR[r] = 0.f; }

#pragma unroll 4
  for (int k = 0; k < DIN_T; ++k) {
    const float wl = Wl[k * DH_C + j];
    const float wr = Wr[k * DH_C + j];
#pragma unroll
    for (int r = 0; r < TILE; ++r) {
      const float a = agg[(long long)(row0 + r) * DIN_T + k];  // uniform
      const float xv = xt[(long long)(row0 + r) * DIN_T + k];  // uniform
      accL[r] = fmaf(a, wl, accL[r]);
      accR[r] = fmaf(xv, wr, accR[r]);
    }
  }

  const float b = bl[j];
#pragma unroll
  for (int r = 0; r < TILE; ++r) {
    const int row = row0 + r;
    const float scale = 1.0f / fmaxf(cnt[row], 1.0f);
    const float h = fmaf(accL[r], scale, accR[r]) + b;
    out[(long long)row * DH_C + j] = fmaxf(h, 0.0f);
  }
}

// ---------------------------------------------------------------------------
// Final layer: 47-wide dual linear + log_softmax. One wave per row.
// ---------------------------------------------------------------------------
__global__ __launch_bounds__(64) void transform2_logsoftmax(
    const float* __restrict__ agg, const float* __restrict__ cnt,
    const float* __restrict__ xt, const float* __restrict__ Wl,
    const float* __restrict__ Wr, const float* __restrict__ bl,
    float* __restrict__ out) {
  const int row = blockIdx.x;
  const int lane = threadIdx.x;       // 0..63
  const int j = lane < DOUT_C ? lane : DOUT_C - 1;

  float accL = 0.f, accR = 0.f;
#pragma unroll 4
  for (int k = 0; k < DH_C; ++k) {
    const float a = agg[row * DH_C + k];   // uniform
    const float xv = xt[row * DH_C + k];   // uniform
    accL = fmaf(a, Wl[k * DOUT_C + j], accL);
    accR = fmaf(xv, Wr[k * DOUT_C + j], accR);
  }
  const float scale = 1.0f / fmaxf(cnt[row], 1.0f);
  const float h = fmaf(accL, scale, accR) + bl[j];

  // wave-wide max over the 47 valid lanes
  float hm = (lane < DOUT_C) ? h : -INFINITY;
#pragma unroll
  for (int off = 32; off > 0; off >>= 1) hm = fmaxf(hm, __shfl_down(hm, off));
  hm = __shfl(hm, 0);

  float e = (lane < DOUT_C) ? expf(h - hm) : 0.f;
#pragma unroll
  for (int off = 32; off > 0; off >>= 1) e += __shfl_down(e, off);
  const float lse = logf(__shfl(e, 0));

  if (lane < DOUT_C) out[row * DOUT_C + lane] = h - hm - lse;
}

// ---------------------------------------------------------------------------
extern "C" void kernel_launch(void* const* d_in, const int* in_sizes, int n_in,
                              void* d_out, int out_size, void* d_ws,
                              size_t ws_size, hipStream_t stream) {
  const float* x    = (const float*)d_in[0];
  const int*   src0 = (const int*)d_in[1];
  const int*   dst0 = (const int*)d_in[2];
  const int*   src1 = (const int*)d_in[3];
  const int*   dst1 = (const int*)d_in[4];
  const int*   src2 = (const int*)d_in[5];
  const int*   dst2 = (const int*)d_in[6];
  const float* Wl0  = (const float*)d_in[7];
  const float* bl0  = (const float*)d_in[8];
  const float* Wr0  = (const float*)d_in[9];
  const float* Wl1  = (const float*)d_in[10];
  const float* bl1  = (const float*)d_in[11];
  const float* Wr1  = (const float*)d_in[12];
  const float* Wl2  = (const float*)d_in[13];
  const float* bl2  = (const float*)d_in[14];
  const float* Wr2  = (const float*)d_in[15];

  // Workspace layout (floats). Zero-init block first (accumulators + counts),
  // then pure-output buffers (fully overwritten each call).
  float* ws = (float*)d_ws;
  float* agg0 = ws;                                   // N1*100 = 20,480,000
  float* agg1 = agg0 + (size_t)N1_C * DIN_C;          // N2*256 =  5,242,880
  float* agg2 = agg1 + (size_t)N2_C * DH_C;           // N3*256 =  1,048,576
  float* cnt0 = agg2 + (size_t)N3_C * DH_C;           // N1
  float* cnt1 = cnt0 + N1_C;                          // N2
  float* cnt2 = cnt1 + N2_C;                          // N3
  float* h1   = cnt2 + N3_C;                          // N1*256 = 52,428,800
  float* h2   = h1 + (size_t)N1_C * DH_C;             // N2*256 =  5,242,880

  const size_t zero_floats = (size_t)N1_C * DIN_C + (size_t)N2_C * DH_C +
                             (size_t)N3_C * DH_C + N1_C + N2_C + N3_C;
  hipMemsetAsync(d_ws, 0, zero_floats * sizeof(float), stream);

  // ---- Layer 0 ----
  scatter_mean_accum<DIN_C><<<(E0_C + 3) / 4, 256, 0, stream>>>(
      x, src0, dst0, agg0, cnt0, E0_C);
  transform_relu<DIN_C><<<N1_C / 8, 256, 0, stream>>>(
      agg0, cnt0, x, Wl0, Wr0, bl0, h1);

  // ---- Layer 1 ----
  scatter_mean_accum<DH_C><<<(E1_C + 3) / 4, 256, 0, stream>>>(
      h1, src1, dst1, agg1, cnt1, E1_C);
  transform_relu<DH_C><<<N2_C / 8, 256, 0, stream>>>(
      agg1, cnt1, h1, Wl1, Wr1, bl1, h2);

  // ---- Layer 2 ----
  scatter_mean_accum<DH_C><<<(E2_C + 3) / 4, 256, 0, stream>>>(
      h2, src2, dst2, agg2, cnt2, E2_C);
  transform2_logsoftmax<<<N3_C, 64, 0, stream>>>(
      agg2, cnt2, h2, Wl2, Wr2, bl2, (float*)d_out);
}